// Round 14
// baseline (31.789 us; speedup 1.0000x reference)
//
#include <hip/hip_runtime.h>
#include <hip/hip_fp16.h>
#include <math.h>

#define HALF_PI   1.57079632679489662f
#define INV_SQRT2 0.70710678118654752f
#define LOG2E     1.44269504088896341f
#define NPART     2048   // edge-kernel blocks; strided EPT=2 covers E <= 1048576

typedef float nfloat4 __attribute__((ext_vector_type(4)));  // native vec for nontemporal

// DPP cross-lane move (VALU, no DS pipe). CTRL: 0x128=row_ror:8 (i^8 in row16),
// 0x141=row_half_mirror (i^7 in 8), 0x1B=quad[3,2,1,0] (i^3), 0xB1=quad[1,0,3,2] (i^1)
template<int CTRL>
__device__ __forceinline__ float dppf(float v) {
    return __int_as_float(__builtin_amdgcn_update_dpp(
        0, __float_as_int(v), CTRL, 0xF, 0xF, false));
}

// ---------------------------------------------------------------------------
// K1: node projections. TWO nodes per wave per iteration. Weight fragments
// preloaded (32 VGPRs). Cross-lane reduction via permlane{32,16}_swap + DPP
// (runtime-probed semantics with __shfl_xor fallback). R12-proven.
// ---------------------------------------------------------------------------
__global__ __launch_bounds__(256) void node_qk(
        const float* __restrict__ feat,
        const float* __restrict__ Wq, const float* __restrict__ bq,
        const float* __restrict__ Wk, const float* __restrict__ bk,
        float* __restrict__ qtab, float* __restrict__ ktab, int N) {
    const int lane  = threadIdx.x & 63;
    const int wid   = (int)((blockIdx.x * blockDim.x + threadIdx.x) >> 6);
    const int nwid  = (int)((gridDim.x * blockDim.x) >> 6);

    const bool hi  = (lane & 32) != 0;
    const bool s16 = (lane & 16) != 0;
    const bool s8  = (lane & 8)  != 0;

    bool use_pl32 = false, use_pl16 = false;
    bool gx32 = !hi;
    bool gx16 = !s16;
#if __has_builtin(__builtin_amdgcn_permlane32_swap)
    {
        float x = (float)lane, y = 2000.0f + (float)lane;
        auto r = __builtin_amdgcn_permlane32_swap(
            __float_as_uint(x), __float_as_uint(y), false, false);
        float ps = __uint_as_float(r[0]) + __uint_as_float(r[1]);
        float xs = (float)(lane + (lane ^ 32));
        bool ok = (ps == xs) || (ps == 4000.0f + xs);
        if (__all(ok)) { use_pl32 = true; gx32 = (ps == xs); }
    }
#endif
#if __has_builtin(__builtin_amdgcn_permlane16_swap)
    {
        float x = (float)lane, y = 2000.0f + (float)lane;
        auto r = __builtin_amdgcn_permlane16_swap(
            __float_as_uint(x), __float_as_uint(y), false, false);
        float ps = __uint_as_float(r[0]) + __uint_as_float(r[1]);
        float xs = (float)(lane + (lane ^ 16));
        bool ok = (ps == xs) || (ps == 4000.0f + xs);
        if (__all(ok)) { use_pl16 = true; gx16 = (ps == xs); }
    }
#endif
    const int  dot  = (gx32 ? 0 : 4) + (gx16 ? 0 : 2) + (s8 ? 1 : 0);
    const float bias = (dot < 4) ? bq[dot] : bk[dot & 3];

    float4 wq4[4], wk4[4];
    #pragma unroll
    for (int q = 0; q < 4; ++q) {
        wq4[q] = reinterpret_cast<const float4*>(Wq + q * 256)[lane];
        wk4[q] = reinterpret_cast<const float4*>(Wk + q * 256)[lane];
    }

    auto reduce8 = [&](float* acc) -> float {
        float accR[4];
        if (use_pl32) {
            #pragma unroll
            for (int j = 0; j < 4; ++j) {
                auto r = __builtin_amdgcn_permlane32_swap(
                    __float_as_uint(acc[j]), __float_as_uint(acc[j + 4]), false, false);
                accR[j] = __uint_as_float(r[0]) + __uint_as_float(r[1]);
            }
        } else {
            #pragma unroll
            for (int j = 0; j < 4; ++j) {
                float give = hi ? acc[j] : acc[j + 4];
                float r = __shfl_xor(give, 32, 64);
                accR[j] = (hi ? acc[j + 4] : acc[j]) + r;
            }
        }
        float a0, a1;
        if (use_pl16) {
#if __has_builtin(__builtin_amdgcn_permlane16_swap)
            auto r0 = __builtin_amdgcn_permlane16_swap(
                __float_as_uint(accR[0]), __float_as_uint(accR[2]), false, false);
            a0 = __uint_as_float(r0[0]) + __uint_as_float(r0[1]);
            auto r1 = __builtin_amdgcn_permlane16_swap(
                __float_as_uint(accR[1]), __float_as_uint(accR[3]), false, false);
            a1 = __uint_as_float(r1[0]) + __uint_as_float(r1[1]);
#else
            a0 = 0.f; a1 = 0.f;
#endif
        } else {
            float give0 = s16 ? accR[0] : accR[2];
            float r0 = __shfl_xor(give0, 16, 64);
            a0 = (s16 ? accR[2] : accR[0]) + r0;
            float give1 = s16 ? accR[1] : accR[3];
            float r1 = __shfl_xor(give1, 16, 64);
            a1 = (s16 ? accR[3] : accR[1]) + r1;
        }
        float give3 = s8 ? a0 : a1;
        float r3 = dppf<0x128>(give3);
        float v = (s8 ? a1 : a0) + r3;
        v += dppf<0x141>(v);
        v += dppf<0x1B>(v);
        v += dppf<0xB1>(v);
        return v;
    };

    for (int nb = wid * 2; nb < N; nb += nwid * 2) {
        const int n1ok = (nb + 1 < N);
        float4 f0 = reinterpret_cast<const float4*>(feat)[(size_t)nb * 64 + lane];
        float4 f1 = n1ok ? reinterpret_cast<const float4*>(feat)[(size_t)(nb + 1) * 64 + lane]
                         : make_float4(0.f, 0.f, 0.f, 0.f);

        float acc0[8], acc1[8];
        #pragma unroll
        for (int q = 0; q < 4; ++q) {
            acc0[q]     = f0.x * wq4[q].x + f0.y * wq4[q].y + f0.z * wq4[q].z + f0.w * wq4[q].w;
            acc0[4 + q] = f0.x * wk4[q].x + f0.y * wk4[q].y + f0.z * wk4[q].z + f0.w * wk4[q].w;
            acc1[q]     = f1.x * wq4[q].x + f1.y * wq4[q].y + f1.z * wq4[q].z + f1.w * wq4[q].w;
            acc1[4 + q] = f1.x * wk4[q].x + f1.y * wk4[q].y + f1.z * wk4[q].z + f1.w * wk4[q].w;
        }

        float v0 = reduce8(acc0);
        float v1 = reduce8(acc1);

        if ((lane & 7) == 0) {
            float t0 = tanhf(v0 + bias) * HALF_PI;
            if (dot < 4) qtab[(size_t)nb * 4 + dot] = t0;
            else         ktab[(size_t)nb * 4 + (dot & 3)] = t0;
            if (n1ok) {
                float t1 = tanhf(v1 + bias) * HALF_PI;
                if (dot < 4) qtab[(size_t)(nb + 1) * 4 + dot] = t1;
                else         ktab[(size_t)(nb + 1) * 4 + (dot & 3)] = t1;
            }
        }
    }
}

// ---------------------------------------------------------------------------
// 4-qubit real circuit. W/cx pre-scaled by 0.25*log2(e) so the result is
// exp2(attn2). Walsh-weight Z reduction (W[~x] = -W[x]).
// ---------------------------------------------------------------------------
__device__ __forceinline__ float edge_ex(float4 qv, float4 kv,
                                         const float* W, const float* cx) {
    float u[4][2];
    {
        float qa[4] = {qv.x, qv.y, qv.z, qv.w};
        #pragma unroll
        for (int w = 0; w < 4; ++w) {
            float s, c;
            __sincosf(qa[w] * 0.5f, &s, &c);
            u[w][0] = (c + s) * INV_SQRT2;
            u[w][1] = (c - s) * INV_SQRT2;
        }
    }
    float c01[4] = {u[0][0]*u[1][0], u[0][0]*u[1][1], u[0][1]*u[1][0], u[0][1]*u[1][1]};
    float c23[4] = {u[2][0]*u[3][0], u[2][0]*u[3][1], u[2][1]*u[3][0], u[2][1]*u[3][1]};
    float a[16];
    #pragma unroll
    for (int x = 0; x < 16; ++x) a[x] = c01[x >> 2] * c23[x & 3];

    {
        float ka[4] = {kv.x, kv.y, kv.z, kv.w};
        #pragma unroll
        for (int w = 0; w < 4; ++w) {
            float si, co;
            __sincosf(ka[w] * 0.5f, &si, &co);
            const int cb = 1 << (3 - w);
            const int tb = 1 << (3 - ((w + 1) & 3));
            #pragma unroll
            for (int x = 0; x < 16; ++x) {
                if ((x & cb) && !(x & tb)) {
                    float a0 = a[x], a1 = a[x | tb];
                    a[x]      = co * a0 - si * a1;
                    a[x | tb] = si * a0 + co * a1;
                }
            }
        }
    }

    float attn2 = 0.f;
    #pragma unroll
    for (int x = 0; x < 8; ++x) {
        float pu = a[15 - x] * a[15 - x];
        float d  = __builtin_fmaf(a[x], a[x], -pu);
        attn2 = __builtin_fmaf(W[x], d, attn2);
    }
    #pragma unroll
    for (int q = 0; q < 4; ++q) {
        const int bit = 1 << (3 - q);
        float sx = 0.f;
        #pragma unroll
        for (int x = 0; x < 16; ++x)
            if (!(x & bit)) sx = __builtin_fmaf(a[x], a[x | bit], sx);
        attn2 = __builtin_fmaf(cx[q], sx, attn2);
    }
    return exp2f(attn2);
}

// ---------------------------------------------------------------------------
// K2: per-edge circuit, STRIDED 2 edges/thread across 2048 blocks
// (8 blocks/CU = 32 waves/CU for gather-latency cover). fp16 ex store;
// partials sum the ROUNDED values.
// ---------------------------------------------------------------------------
__global__ __launch_bounds__(256) void edge_attn(
        const int* __restrict__ ei,
        const float4* __restrict__ qtab, const float4* __restrict__ ktab,
        const float* __restrict__ qp,
        __half* __restrict__ exh, float* __restrict__ partial, int E) {
    __shared__ float scz[4], scxs[4];
    __shared__ float red[256];
    const int tid = threadIdx.x;
    if (tid < 4) {
        float phi = qp[3 * tid + 0];
        float th  = qp[3 * tid + 1];
        float sth, cth;
        sincosf(th, &sth, &cth);
        scz[tid]  = 0.25f * LOG2E * cth;            // 0.25 and log2(e) folded
        scxs[tid] = -0.5f * LOG2E * sth * cosf(phi);
    }
    __syncthreads();

    const float z0 = scz[0], z1 = scz[1], z2 = scz[2], z3 = scz[3];
    const float u0 = z2 + z3, u1 = z2 - z3;
    const float w00 = z1 + u0, w01 = z1 + u1, w10 = z1 - u1, w11 = z1 - u0;
    const float W[8] = {z0 + w00, z0 + w01, z0 + w10, z0 + w11,
                        z0 - w11, z0 - w10, z0 - w01, z0 - w00};
    const float cx[4] = {scxs[0], scxs[1], scxs[2], scxs[3]};

    const int gtid  = blockIdx.x * 256 + tid;
    const int total = NPART * 256;

    int sidx[2], didx[2];
    #pragma unroll
    for (int it = 0; it < 2; ++it) {
        const int e  = gtid + it * total;
        const int ee = (e < E) ? e : (E - 1);
        sidx[it] = ei[ee];
        didx[it] = ei[E + ee];
    }

    float lsum = 0.f;
    #pragma unroll
    for (int it = 0; it < 2; ++it) {
        const int e = gtid + it * total;
        if (e < E) {
            float v = edge_ex(qtab[sidx[it]], ktab[didx[it]], W, cx);
            __half h = __float2half(v);
            exh[e] = h;
            lsum += __half2float(h);
        }
    }

    red[tid] = lsum;
    __syncthreads();
    #pragma unroll
    for (int s = 128; s > 0; s >>= 1) {
        if (tid < s) red[tid] += red[tid + s];
        __syncthreads();
    }
    if (tid == 0) partial[blockIdx.x] = red[0];
}

// ---------------------------------------------------------------------------
// K3: redundant deterministic reduce of NPART partials (8/thread), then
// out = exh * inv with nontemporal native-vec4 stores (out never re-read).
// ---------------------------------------------------------------------------
__global__ __launch_bounds__(256) void normalize_out(
        const __half* __restrict__ exh, const float* __restrict__ partial,
        float* __restrict__ out, int E) {
    __shared__ float red[256];
    const int tid = threadIdx.x;
    float s = 0.f;
    #pragma unroll
    for (int k = 0; k < NPART / 256; ++k) s += partial[tid + k * 256];
    red[tid] = s;
    __syncthreads();
    #pragma unroll
    for (int st = 128; st > 0; st >>= 1) {
        if (tid < st) red[tid] += red[tid + st];
        __syncthreads();
    }
    const float inv = 1.f / red[0];

    const int nv8    = E >> 3;
    const int stride = (int)(gridDim.x * 256);
    const uint4* exh8 = reinterpret_cast<const uint4*>(exh);
    nfloat4* out4 = reinterpret_cast<nfloat4*>(out);
    for (int i = blockIdx.x * 256 + tid; i < nv8; i += stride) {
        uint4 hv = exh8[i];
        __half2 h0 = *reinterpret_cast<__half2*>(&hv.x);
        __half2 h1 = *reinterpret_cast<__half2*>(&hv.y);
        __half2 h2 = *reinterpret_cast<__half2*>(&hv.z);
        __half2 h3 = *reinterpret_cast<__half2*>(&hv.w);
        float2 f0 = __half22float2(h0);
        float2 f1 = __half22float2(h1);
        float2 f2 = __half22float2(h2);
        float2 f3 = __half22float2(h3);
        nfloat4 o0 = {f0.x * inv, f0.y * inv, f1.x * inv, f1.y * inv};
        nfloat4 o1 = {f2.x * inv, f2.y * inv, f3.x * inv, f3.y * inv};
        __builtin_nontemporal_store(o0, &out4[2 * i]);
        __builtin_nontemporal_store(o1, &out4[2 * i + 1]);
    }
    const int tail = nv8 << 3;
    for (int e = tail + blockIdx.x * 256 + tid; e < E; e += stride)
        out[e] = __half2float(exh[e]) * inv;
}

extern "C" void kernel_launch(void* const* d_in, const int* in_sizes, int n_in,
                              void* d_out, int out_size, void* d_ws, size_t ws_size,
                              hipStream_t stream) {
    const float* feat = (const float*)d_in[0];
    const int*   ei   = (const int*)d_in[1];
    const float* Wq   = (const float*)d_in[2];
    const float* bq   = (const float*)d_in[3];
    const float* Wk   = (const float*)d_in[4];
    const float* bk   = (const float*)d_in[5];
    const float* qp   = (const float*)d_in[6];

    int D = in_sizes[2] / 4;          // 256
    int N = in_sizes[0] / D;          // 50000
    int E = in_sizes[1] / 2;          // 800000
    (void)D;

    float*  ws      = (float*)d_ws;
    float*  partial = ws;                          // NPART floats (8 KB)
    float*  qtab    = ws + NPART;                  // 4N floats (16B aligned)
    float*  ktab    = qtab + (size_t)N * 4;        // 4N floats
    __half* exh     = (__half*)(ktab + (size_t)N * 4);  // E halfs (16B aligned)
    float*  out     = (float*)d_out;

    node_qk<<<2048, 256, 0, stream>>>(feat, Wq, bq, Wk, bk, qtab, ktab, N);
    edge_attn<<<NPART, 256, 0, stream>>>(ei, (const float4*)qtab, (const float4*)ktab,
                                         qp, exh, partial, E);
    normalize_out<<<2048, 256, 0, stream>>>(exh, partial, out, E);
}